// Round 14
// baseline (158.896 us; speedup 1.0000x reference)
//
#include <hip/hip_runtime.h>
#include <hip/hip_bf16.h>

#define NE 100000
#define NK 16
#define ND 128
#define NTILES 6250   // NE / 16
#define NSUP 3125     // NE / 32

typedef __bf16 bf16_t;
typedef bf16_t bf16x8 __attribute__((ext_vector_type(8)));
typedef bf16_t bf16x4 __attribute__((ext_vector_type(4)));
typedef float f32x4 __attribute__((ext_vector_type(4)));
typedef float f32x2 __attribute__((ext_vector_type(2)));
typedef unsigned u32x2 __attribute__((ext_vector_type(2)));
typedef unsigned short u16;
typedef unsigned char u8;

__device__ __forceinline__ u16 f2bf(float f) {
  bf16_t h = (bf16_t)f;
  return __builtin_bit_cast(u16, h);
}

// lgkmcnt-only barrier: LDS visible, global loads ride across.
__device__ __forceinline__ void soft_barrier() {
  asm volatile("s_waitcnt lgkmcnt(0)" ::: "memory");
  __builtin_amdgcn_s_barrier();
}

// unpack 8 fp8 (2 dwords) of S into two f32x4
__device__ __forceinline__ void unpack_s(unsigned w0, unsigned w1,
                                         f32x4& sA, f32x4& sB) {
  const f32x2 a0 = __builtin_amdgcn_cvt_pk_f32_fp8(w0, false);
  const f32x2 a1 = __builtin_amdgcn_cvt_pk_f32_fp8(w0, true);
  const f32x2 a2 = __builtin_amdgcn_cvt_pk_f32_fp8(w1, false);
  const f32x2 a3 = __builtin_amdgcn_cvt_pk_f32_fp8(w1, true);
  sA[0] = a0[0]; sA[1] = a0[1]; sA[2] = a1[0]; sA[3] = a1[1];
  sB[0] = a2[0]; sB[1] = a2[1]; sB[2] = a3[0]; sB[3] = a3[1];
}

// hacc += relu(s + z) for 8 channels (vector form -> v_pk_add_f32)
__device__ __forceinline__ void acc8(f32x4& hA, f32x4& hB,
                                     const f32x4 sA, const f32x4 sB,
                                     const u32x2 zw) {
  const f32x2 z0 = __builtin_amdgcn_cvt_pk_f32_fp8(zw[0], false);
  const f32x2 z1 = __builtin_amdgcn_cvt_pk_f32_fp8(zw[0], true);
  const f32x2 z2 = __builtin_amdgcn_cvt_pk_f32_fp8(zw[1], false);
  const f32x2 z3 = __builtin_amdgcn_cvt_pk_f32_fp8(zw[1], true);
  f32x4 vA = sA, vB = sB;
  vA[0] += z0[0]; vA[1] += z0[1]; vA[2] += z1[0]; vA[3] += z1[1];
  vB[0] += z2[0]; vB[1] += z2[1]; vB[2] += z3[0]; vB[3] += z3[1];
#pragma unroll
  for (int i = 0; i < 4; ++i) {
    vA[i] = fmaxf(vA[i], 0.f);
    vB[i] = fmaxf(vB[i], 0.f);
  }
  hA += vA;
  hB += vB;
}

// ---------------------------------------------------------------------------
// k_prep: bf16-convert weights; fold Wp = Um@mW2, bp = ub1 + Um@mb2.
// ---------------------------------------------------------------------------
__global__ void k_prep(const float* __restrict__ mW1, const float* __restrict__ uW1,
                       const float* __restrict__ uW2, const float* __restrict__ mW2,
                       const float* __restrict__ ub1, const float* __restrict__ mb2,
                       u16* __restrict__ Wi_b, u16* __restrict__ Wj_b,
                       u16* __restrict__ Ui_b, u16* __restrict__ Wp_b,
                       u16* __restrict__ W2_b, float* __restrict__ bp)
{
  const int o = blockIdx.x, t = threadIdx.x;
  Wi_b[o * ND + t] = f2bf(mW1[o * 256 + t]);
  Wj_b[o * ND + t] = f2bf(mW1[o * 256 + 128 + t]);
  Ui_b[o * ND + t] = f2bf(uW1[o * 256 + t]);
  W2_b[o * ND + t] = f2bf(uW2[o * ND + t]);
  float acc = 0.f;
  for (int p = 0; p < 128; ++p)
    acc += uW1[o * 256 + 128 + p] * mW2[p * 128 + t];
  Wp_b[o * ND + t] = f2bf(acc);
  if (t == 0) {
    float b = ub1[o];
    for (int p = 0; p < 128; ++p) b += uW1[o * 256 + 128 + p] * mb2[p];
    bp[o] = b;
  }
}

// ---------------------------------------------------------------------------
// k1: S = X@Wi^T + mb1 (fp8), Z = X@Wj^T (fp8), T1 = X@Ui^T + bp (bf16,
// FRAG-LINEAR packed: thread tid's 8B at Tp + t*2048 + tid*4 — contiguous
// 4KB/tile; matches k23's per-lane acc-init read (coalesced 512B/wave)).
// Soft (lgkm-only) barrier keeps the 2-deep X prefetch alive.
// ---------------------------------------------------------------------------
__global__ __launch_bounds__(512) void k1_szt(
    const float* __restrict__ X, const u16* __restrict__ Wi_b,
    const u16* __restrict__ Wj_b, const u16* __restrict__ Ui_b,
    const float* __restrict__ mb1, const float* __restrict__ bp,
    u8* __restrict__ Sf8, u8* __restrict__ Zf8, u16* __restrict__ Tp)
{
  __shared__ u16 xt[2][16 * ND];
  __shared__ u8  eS[2][16 * ND];
  __shared__ u8  eZ[2][16 * ND];
  __shared__ u16 eT[2][16 * ND];
  const int tid = threadIdx.x, wid = tid >> 6, lane = tid & 63;
  const int r = lane & 15, q = lane >> 4;

  bf16x8 wiF[4], wjF[4], uiF[4];
  f32x4 mbF, bpF;
  {
    const int row = wid * 16 + r;
#pragma unroll
    for (int kk = 0; kk < 4; ++kk) {
      wiF[kk] = *(const bf16x8*)(Wi_b + row * ND + kk * 32 + q * 8);
      wjF[kk] = *(const bf16x8*)(Wj_b + row * ND + kk * 32 + q * 8);
      uiF[kk] = *(const bf16x8*)(Ui_b + row * ND + kk * 32 + q * 8);
    }
    mbF = *(const f32x4*)(mb1 + wid * 16 + q * 4);
    bpF = *(const f32x4*)(bp  + wid * 16 + q * 4);
  }

  const int rs = tid >> 5, cs = tid & 31;
  const int stb = rs * 256 + ((((cs >> 1) ^ (rs & 15)) << 4) | ((cs & 1) << 3));
  const int ewb = r * 256 + ((((wid * 2 + (q >> 1)) ^ (r & 15)) << 4) | ((q & 1) << 3));
  const int ezb = r * 128 + (((wid ^ (r & 7)) << 4) | (q * 4));
  const int erow = tid >> 5, c8 = tid & 31;
  const int erb = erow * 256 + ((((c8 >> 1) ^ (erow & 15)) << 4) | ((c8 & 1) << 3));
  const int zrb = erow * 128 + ((((c8 >> 2) ^ (erow & 7)) << 4) | ((c8 & 3) << 2));
  // frag-linear T read: thread tid -> (edge tid&15, chbase (tid>>4)*4)
  const int trb2 = (tid & 15) * 256 +
                   ((((tid >> 5) ^ (tid & 15)) << 4) | (((tid >> 4) & 1) << 3));

  const long stride = gridDim.x;
  long t = blockIdx.x;
  if (t >= NTILES) return;

  f32x4 xr;
  auto gload = [&](long tt) {
    xr = *(const f32x4*)(X + (tt * 16 + rs) * ND + cs * 4);
  };
  auto stage = [&](int bb) {
    bf16x4 b;
#pragma unroll
    for (int i = 0; i < 4; ++i) b[i] = (bf16_t)xr[i];
    *(bf16x4*)((char*)xt[bb] + stb) = b;
  };

  gload(t);
  stage(0);
  {
    const long t1 = t + stride;
    if (t1 < NTILES) gload(t1);
  }
  soft_barrier();
  int b = 0;

  for (; t < NTILES; t += stride) {
    const long tn = t + stride, tn2 = tn + stride;

    bf16x8 xf[4];
#pragma unroll
    for (int kk = 0; kk < 4; ++kk)
      xf[kk] = *(const bf16x8*)((const char*)xt[b] +
               r * 256 + (((kk * 4 + q) ^ (r & 15)) << 4));

    if (tn < NTILES) stage(b ^ 1);
    if (tn2 < NTILES) gload(tn2);

    f32x4 aS = {0.f, 0.f, 0.f, 0.f};
    f32x4 aZ = {0.f, 0.f, 0.f, 0.f};
    f32x4 aT = {0.f, 0.f, 0.f, 0.f};
#pragma unroll
    for (int kk = 0; kk < 4; ++kk) {
      aS = __builtin_amdgcn_mfma_f32_16x16x32_bf16(wiF[kk], xf[kk], aS, 0, 0, 0);
      aZ = __builtin_amdgcn_mfma_f32_16x16x32_bf16(wjF[kk], xf[kk], aZ, 0, 0, 0);
      aT = __builtin_amdgcn_mfma_f32_16x16x32_bf16(uiF[kk], xf[kk], aT, 0, 0, 0);
    }

    bf16x4 pT;
#pragma unroll
    for (int i = 0; i < 4; ++i) pT[i] = (bf16_t)(aT[i] + bpF[i]);
    unsigned spk = 0, zpk = 0;
    spk = __builtin_amdgcn_cvt_pk_fp8_f32(aS[0] + mbF[0], aS[1] + mbF[1], spk, false);
    spk = __builtin_amdgcn_cvt_pk_fp8_f32(aS[2] + mbF[2], aS[3] + mbF[3], spk, true);
    zpk = __builtin_amdgcn_cvt_pk_fp8_f32(aZ[0], aZ[1], zpk, false);
    zpk = __builtin_amdgcn_cvt_pk_fp8_f32(aZ[2], aZ[3], zpk, true);
    *(unsigned*)((char*)eS[b] + ezb) = spk;
    *(unsigned*)((char*)eZ[b] + ezb) = zpk;
    *(bf16x4*)((char*)eT[b] + ewb) = pT;

    soft_barrier();   // single lgkm-only barrier per tile

    {
      const long e = t * 16 + erow;
      const unsigned vS = *(const unsigned*)((const char*)eS[b] + zrb);
      const unsigned vZ = *(const unsigned*)((const char*)eZ[b] + zrb);
      const bf16x4 vT = *(const bf16x4*)((const char*)eT[b] + trb2);
      *(unsigned*)(Sf8 + e * ND + c8 * 4) = vS;
      *(unsigned*)(Zf8 + e * ND + c8 * 4) = vZ;
      *(bf16x4*)(Tp + t * 2048 + tid * 4) = vT;   // contiguous 4KB/tile
    }
    b ^= 1;
  }
}

// ---------------------------------------------------------------------------
// k23: fused gather + both GEMMs, r14 VGPR-diet edition.
// 512 thr / 8 waves / 32-edge supertile. Changes vs r13: tt LDS removed
// (T1 acc-init read directly from frag-linear Tp, prefetched in regs);
// single 8-deep zbuf reused for both bursts (consume-A after B1 frees it);
// consume math vectorized (v_pk_add_f32); __launch_bounds__(512,6) to
// target 3 blocks/CU (24 waves) for gather MLP.
// ---------------------------------------------------------------------------
__global__ __launch_bounds__(512, 6) void k23_fused(
    const u8* __restrict__ Zf8, const u8* __restrict__ Sf8,
    const int* __restrict__ adj, const u16* __restrict__ Tp,
    const u16* __restrict__ Wp_b, const u16* __restrict__ W2_b,
    const float* __restrict__ ub2, float* __restrict__ out)
{
  __shared__ u16 ht[32 * ND];   // 8 KB  hbar (bf16, swizzled)
  __shared__ u16 ut[32 * ND];   // 8 KB  u exchange
  const int tid = threadIdx.x, wid = tid >> 6, lane = tid & 63;
  const int r = lane & 15, q = lane >> 4;
  const int ew = wid * 4 + q;          // edge-in-supertile
  const int c0 = r * 8;                // gather channel base (8 fp8 bytes)

  bf16x8 wpF[4], w2F[4];
  f32x4 ubF;
  {
    const int row = wid * 16 + r;
#pragma unroll
    for (int kk = 0; kk < 4; ++kk) {
      wpF[kk] = *(const bf16x8*)(Wp_b + row * ND + kk * 32 + q * 8);
      w2F[kk] = *(const bf16x8*)(W2_b + row * ND + kk * 32 + q * 8);
    }
    ubF = *(const f32x4*)(ub2 + wid * 16 + q * 4);
  }

  const int hwb = ew * 256 + ((r ^ (ew & 15)) << 4);
  const int uwb0 = (((wid * 2 + (q >> 1)) ^ r) << 4) | ((q & 1) << 3);
  const int tpo = wid * 256 + q * 64 + r * 4;   // frag-linear Tp lane offset

  const long stride = gridDim.x;
  long s = blockIdx.x;
  if (s >= NSUP) return;

  auto adjload = [&](long ss) { return adj[(ss * 32 + ew) * NK + r]; };

  // ---- prologue: gather supertile s in two 8-bursts ----
  int myidxN;
  f32x4 haccA = {0.f, 0.f, 0.f, 0.f}, haccB = {0.f, 0.f, 0.f, 0.f};
  bf16x4 trC0, trC1;
  {
    const int myidxC = adjload(s);
    const unsigned* sp = (const unsigned*)(Sf8 + (s * 32 + ew) * ND + c0);
    const unsigned sw0 = sp[0], sw1 = sp[1];
    trC0 = *(const bf16x4*)(Tp + s * 4096 + tpo);
    trC1 = *(const bf16x4*)(Tp + s * 4096 + 2048 + tpo);
    myidxN = (s + stride < NSUP) ? adjload(s + stride) : 0;

    f32x4 sA, sB;
    unpack_s(sw0, sw1, sA, sB);
    u32x2 zb[8];
#pragma unroll
    for (int k = 0; k < 8; ++k) {
      const int n = __shfl(myidxC, (lane & 48) + k);
      zb[k] = *(const u32x2*)(Zf8 + (long)n * ND + c0);
    }
#pragma unroll
    for (int k = 0; k < 8; ++k) acc8(haccA, haccB, sA, sB, zb[k]);
#pragma unroll
    for (int k = 0; k < 8; ++k) {
      const int n = __shfl(myidxC, (lane & 48) + 8 + k);
      zb[k] = *(const u32x2*)(Zf8 + (long)n * ND + c0);
    }
#pragma unroll
    for (int k = 0; k < 8; ++k) acc8(haccA, haccB, sA, sB, zb[k]);
  }

  for (; s < NSUP; s += stride) {
    const long sn = s + stride, sn2 = sn + stride;
    const bool hasN = (sn < NSUP);

    // ---- A-store: hbar -> ht ----
    {
      bf16x8 hv;
#pragma unroll
      for (int i = 0; i < 4; ++i) {
        hv[i]     = (bf16_t)(haccA[i] * 0.0625f);
        hv[i + 4] = (bf16_t)(haccB[i] * 0.0625f);
      }
      *(bf16x8*)((char*)ht + hwb) = hv;
    }

    // ---- prefetch for sn: S, Tp, adj(sn2), Z burst A ----
    u32x2 zbuf[8];
    unsigned swn0 = 0, swn1 = 0;
    bf16x4 trN0 = {}, trN1 = {};
    int myidxN2 = 0;
    if (hasN) {
      const unsigned* sp = (const unsigned*)(Sf8 + (sn * 32 + ew) * ND + c0);
      swn0 = sp[0]; swn1 = sp[1];
      trN0 = *(const bf16x4*)(Tp + sn * 4096 + tpo);
      trN1 = *(const bf16x4*)(Tp + sn * 4096 + 2048 + tpo);
      if (sn2 < NSUP) myidxN2 = adjload(sn2);
#pragma unroll
      for (int k = 0; k < 8; ++k) {
        const int n = __shfl(myidxN, (lane & 48) + k);
        zbuf[k] = *(const u32x2*)(Zf8 + (long)n * ND + c0);
      }
    }

    soft_barrier();   // ht visible; loads ride across

    // ---- B1: u = relu(T1 + hbar@Wp^T), both sub-tiles ----
#pragma unroll
    for (int t2 = 0; t2 < 2; ++t2) {
      const int rowb = (t2 * 16 + r) * 256;
      bf16x8 hf[4];
#pragma unroll
      for (int kk = 0; kk < 4; ++kk)
        hf[kk] = *(const bf16x8*)((const char*)ht + rowb + (((kk * 4 + q) ^ r) << 4));
      const bf16x4 tv = t2 ? trC1 : trC0;
      f32x4 acc;
#pragma unroll
      for (int i = 0; i < 4; ++i) acc[i] = (float)tv[i];
#pragma unroll
      for (int kk = 0; kk < 4; ++kk)
        acc = __builtin_amdgcn_mfma_f32_16x16x32_bf16(wpF[kk], hf[kk], acc, 0, 0, 0);
      bf16x4 u;
#pragma unroll
      for (int i = 0; i < 4; ++i) u[i] = (bf16_t)fmaxf(acc[i], 0.f);
      *(bf16x4*)((char*)ut + rowb + uwb0) = u;
    }

    // ---- consume burst A, then issue burst B (zbuf reused) ----
    f32x4 sA, sB;
    if (hasN) {
      unpack_s(swn0, swn1, sA, sB);
      haccA = f32x4{0.f, 0.f, 0.f, 0.f};
      haccB = f32x4{0.f, 0.f, 0.f, 0.f};
#pragma unroll
      for (int k = 0; k < 8; ++k) acc8(haccA, haccB, sA, sB, zbuf[k]);
#pragma unroll
      for (int k = 0; k < 8; ++k) {
        const int n = __shfl(myidxN, (lane & 48) + 8 + k);
        zbuf[k] = *(const u32x2*)(Zf8 + (long)n * ND + c0);
      }
    }

    soft_barrier();   // ut visible

    // ---- B2: out = u@uW2^T + ub2 ----
#pragma unroll
    for (int t2 = 0; t2 < 2; ++t2) {
      const int rowb = (t2 * 16 + r) * 256;
      bf16x8 uf[4];
#pragma unroll
      for (int kk = 0; kk < 4; ++kk)
        uf[kk] = *(const bf16x8*)((const char*)ut + rowb + (((kk * 4 + q) ^ r) << 4));
      f32x4 o = {0.f, 0.f, 0.f, 0.f};
#pragma unroll
      for (int kk = 0; kk < 4; ++kk)
        o = __builtin_amdgcn_mfma_f32_16x16x32_bf16(w2F[kk], uf[kk], o, 0, 0, 0);
#pragma unroll
      for (int i = 0; i < 4; ++i) o[i] += ubF[i];
      *(f32x4*)(out + (s * 32 + t2 * 16 + r) * ND + wid * 16 + q * 4) = o;
    }

    // ---- consume burst B ----
    if (hasN) {
#pragma unroll
      for (int k = 0; k < 8; ++k) acc8(haccA, haccB, sA, sB, zbuf[k]);
      myidxN = myidxN2;
      trC0 = trN0;
      trC1 = trN1;
    }
  }
}

extern "C" void kernel_launch(void* const* d_in, const int* in_sizes, int n_in,
                              void* d_out, int out_size, void* d_ws, size_t ws_size,
                              hipStream_t stream)
{
  (void)in_sizes; (void)n_in; (void)out_size; (void)ws_size;
  const float* X   = (const float*)d_in[0];
  const int*   adj = (const int*)d_in[1];
  const float* mW1 = (const float*)d_in[2];
  const float* mb1 = (const float*)d_in[3];
  const float* mW2 = (const float*)d_in[4];
  const float* mb2 = (const float*)d_in[5];
  const float* uW1 = (const float*)d_in[6];
  const float* ub1 = (const float*)d_in[7];
  const float* uW2 = (const float*)d_in[8];
  const float* ub2 = (const float*)d_in[9];
  float* out = (float*)d_out;

  u8* ws8  = (u8*)d_ws;
  u8* Sf8  = ws8;                                // E*ND fp8 (12.8 MB)
  u8* Zf8  = Sf8 + (size_t)NE * ND;              // E*ND fp8 (12.8 MB)
  u16* Tp  = (u16*)(Zf8 + (size_t)NE * ND);      // packed T1 bf16 (25.6 MB, 2048 u16/tile)
  u16* Wi_b = Tp + (size_t)NE * ND;              // 128*128 bf16 each:
  u16* Wj_b = Wi_b + 128 * 128;
  u16* Ui_b = Wj_b + 128 * 128;
  u16* Wp_b = Ui_b + 128 * 128;
  u16* W2_b = Wp_b + 128 * 128;
  float* bp = (float*)(W2_b + 128 * 128);        // 128 f32

  k_prep<<<128, 128, 0, stream>>>(mW1, uW1, uW2, mW2, ub1, mb2,
                                  Wi_b, Wj_b, Ui_b, Wp_b, W2_b, bp);

  k1_szt<<<1024, 512, 0, stream>>>(X, Wi_b, Wj_b, Ui_b, mb1, bp, Sf8, Zf8, Tp);

  k23_fused<<<768, 512, 0, stream>>>(Zf8, Sf8, adj, Tp, Wp_b, W2_b, ub2, out);
}

// Round 15
// 85.911 us; speedup vs baseline: 1.8495x; 1.8495x over previous
//
#include <hip/hip_runtime.h>
#include <hip/hip_bf16.h>

#define NE 100000
#define NK 16
#define ND 128
#define NTILES 6250   // NE / 16
#define NSUP 3125     // NE / 32

typedef __bf16 bf16_t;
typedef bf16_t bf16x8 __attribute__((ext_vector_type(8)));
typedef bf16_t bf16x4 __attribute__((ext_vector_type(4)));
typedef float f32x4 __attribute__((ext_vector_type(4)));
typedef float f32x2 __attribute__((ext_vector_type(2)));
typedef unsigned u32x2 __attribute__((ext_vector_type(2)));
typedef unsigned short u16;
typedef unsigned char u8;

__device__ __forceinline__ u16 f2bf(float f) {
  bf16_t h = (bf16_t)f;
  return __builtin_bit_cast(u16, h);
}

// lgkmcnt-only barrier: LDS visible, global loads ride across.
__device__ __forceinline__ void soft_barrier() {
  asm volatile("s_waitcnt lgkmcnt(0)" ::: "memory");
  __builtin_amdgcn_s_barrier();
}

// unpack 8 fp8 (2 dwords) into two f32x4
__device__ __forceinline__ void unpack_s(unsigned w0, unsigned w1,
                                         f32x4& sA, f32x4& sB) {
  const f32x2 a0 = __builtin_amdgcn_cvt_pk_f32_fp8(w0, false);
  const f32x2 a1 = __builtin_amdgcn_cvt_pk_f32_fp8(w0, true);
  const f32x2 a2 = __builtin_amdgcn_cvt_pk_f32_fp8(w1, false);
  const f32x2 a3 = __builtin_amdgcn_cvt_pk_f32_fp8(w1, true);
  sA[0] = a0[0]; sA[1] = a0[1]; sA[2] = a1[0]; sA[3] = a1[1];
  sB[0] = a2[0]; sB[1] = a2[1]; sB[2] = a3[0]; sB[3] = a3[1];
}

// hacc += relu(s + z) for 8 channels (vector form -> v_pk_add_f32)
__device__ __forceinline__ void acc8(f32x4& hA, f32x4& hB,
                                     const f32x4 sA, const f32x4 sB,
                                     const u32x2 zw) {
  const f32x2 z0 = __builtin_amdgcn_cvt_pk_f32_fp8(zw[0], false);
  const f32x2 z1 = __builtin_amdgcn_cvt_pk_f32_fp8(zw[0], true);
  const f32x2 z2 = __builtin_amdgcn_cvt_pk_f32_fp8(zw[1], false);
  const f32x2 z3 = __builtin_amdgcn_cvt_pk_f32_fp8(zw[1], true);
  f32x4 vA = sA, vB = sB;
  vA[0] += z0[0]; vA[1] += z0[1]; vA[2] += z1[0]; vA[3] += z1[1];
  vB[0] += z2[0]; vB[1] += z2[1]; vB[2] += z3[0]; vB[3] += z3[1];
#pragma unroll
  for (int i = 0; i < 4; ++i) {
    vA[i] = fmaxf(vA[i], 0.f);
    vB[i] = fmaxf(vB[i], 0.f);
  }
  hA += vA;
  hB += vB;
}

// ---------------------------------------------------------------------------
// k_prep: bf16-convert weights; fold Wp = Um@mW2, bp = ub1 + Um@mb2.
// ---------------------------------------------------------------------------
__global__ void k_prep(const float* __restrict__ mW1, const float* __restrict__ uW1,
                       const float* __restrict__ uW2, const float* __restrict__ mW2,
                       const float* __restrict__ ub1, const float* __restrict__ mb2,
                       u16* __restrict__ Wi_b, u16* __restrict__ Wj_b,
                       u16* __restrict__ Ui_b, u16* __restrict__ Wp_b,
                       u16* __restrict__ W2_b, float* __restrict__ bp)
{
  const int o = blockIdx.x, t = threadIdx.x;
  Wi_b[o * ND + t] = f2bf(mW1[o * 256 + t]);
  Wj_b[o * ND + t] = f2bf(mW1[o * 256 + 128 + t]);
  Ui_b[o * ND + t] = f2bf(uW1[o * 256 + t]);
  W2_b[o * ND + t] = f2bf(uW2[o * ND + t]);
  float acc = 0.f;
  for (int p = 0; p < 128; ++p)
    acc += uW1[o * 256 + 128 + p] * mW2[p * 128 + t];
  Wp_b[o * ND + t] = f2bf(acc);
  if (t == 0) {
    float b = ub1[o];
    for (int p = 0; p < 128; ++p) b += uW1[o * 256 + 128 + p] * mb2[p];
    bp[o] = b;
  }
}

// ---------------------------------------------------------------------------
// k1: S = X@Wi^T + mb1 (fp8), Z = X@Wj^T (fp8), T1 = X@Ui^T + bp (bf16,
// tight-packed 2048 u16 per 16-edge tile). r13-exact structure: soft
// (lgkm-only) barrier per tile keeps the 2-deep X prefetch alive.
// ---------------------------------------------------------------------------
__global__ __launch_bounds__(512) void k1_szt(
    const float* __restrict__ X, const u16* __restrict__ Wi_b,
    const u16* __restrict__ Wj_b, const u16* __restrict__ Ui_b,
    const float* __restrict__ mb1, const float* __restrict__ bp,
    u8* __restrict__ Sf8, u8* __restrict__ Zf8, u16* __restrict__ Tp)
{
  __shared__ u16 xt[2][16 * ND];
  __shared__ u8  eS[2][16 * ND];
  __shared__ u8  eZ[2][16 * ND];
  __shared__ u16 eT[2][16 * ND];
  const int tid = threadIdx.x, wid = tid >> 6, lane = tid & 63;
  const int r = lane & 15, q = lane >> 4;

  bf16x8 wiF[4], wjF[4], uiF[4];
  f32x4 mbF, bpF;
  {
    const int row = wid * 16 + r;
#pragma unroll
    for (int kk = 0; kk < 4; ++kk) {
      wiF[kk] = *(const bf16x8*)(Wi_b + row * ND + kk * 32 + q * 8);
      wjF[kk] = *(const bf16x8*)(Wj_b + row * ND + kk * 32 + q * 8);
      uiF[kk] = *(const bf16x8*)(Ui_b + row * ND + kk * 32 + q * 8);
    }
    mbF = *(const f32x4*)(mb1 + wid * 16 + q * 4);
    bpF = *(const f32x4*)(bp  + wid * 16 + q * 4);
  }

  const int rs = tid >> 5, cs = tid & 31;
  const int stb = rs * 256 + ((((cs >> 1) ^ (rs & 15)) << 4) | ((cs & 1) << 3));
  const int ewb = r * 256 + ((((wid * 2 + (q >> 1)) ^ (r & 15)) << 4) | ((q & 1) << 3));
  const int ezb = r * 128 + (((wid ^ (r & 7)) << 4) | (q * 4));
  const int erow = tid >> 5, c8 = tid & 31;
  const int erb = erow * 256 + ((((c8 >> 1) ^ (erow & 15)) << 4) | ((c8 & 1) << 3));
  const int zrb = erow * 128 + ((((c8 >> 2) ^ (erow & 7)) << 4) | ((c8 & 3) << 2));

  const long stride = gridDim.x;
  long t = blockIdx.x;
  if (t >= NTILES) return;

  f32x4 xr;
  auto gload = [&](long tt) {
    xr = *(const f32x4*)(X + (tt * 16 + rs) * ND + cs * 4);
  };
  auto stage = [&](int bb) {
    bf16x4 b;
#pragma unroll
    for (int i = 0; i < 4; ++i) b[i] = (bf16_t)xr[i];
    *(bf16x4*)((char*)xt[bb] + stb) = b;
  };

  gload(t);
  stage(0);
  {
    const long t1 = t + stride;
    if (t1 < NTILES) gload(t1);
  }
  soft_barrier();
  int b = 0;

  for (; t < NTILES; t += stride) {
    const long tn = t + stride, tn2 = tn + stride;

    bf16x8 xf[4];
#pragma unroll
    for (int kk = 0; kk < 4; ++kk)
      xf[kk] = *(const bf16x8*)((const char*)xt[b] +
               r * 256 + (((kk * 4 + q) ^ (r & 15)) << 4));

    if (tn < NTILES) stage(b ^ 1);
    if (tn2 < NTILES) gload(tn2);

    f32x4 aS = {0.f, 0.f, 0.f, 0.f};
    f32x4 aZ = {0.f, 0.f, 0.f, 0.f};
    f32x4 aT = {0.f, 0.f, 0.f, 0.f};
#pragma unroll
    for (int kk = 0; kk < 4; ++kk) {
      aS = __builtin_amdgcn_mfma_f32_16x16x32_bf16(wiF[kk], xf[kk], aS, 0, 0, 0);
      aZ = __builtin_amdgcn_mfma_f32_16x16x32_bf16(wjF[kk], xf[kk], aZ, 0, 0, 0);
      aT = __builtin_amdgcn_mfma_f32_16x16x32_bf16(uiF[kk], xf[kk], aT, 0, 0, 0);
    }

    bf16x4 pT;
#pragma unroll
    for (int i = 0; i < 4; ++i) pT[i] = (bf16_t)(aT[i] + bpF[i]);
    unsigned spk = 0, zpk = 0;
    spk = __builtin_amdgcn_cvt_pk_fp8_f32(aS[0] + mbF[0], aS[1] + mbF[1], spk, false);
    spk = __builtin_amdgcn_cvt_pk_fp8_f32(aS[2] + mbF[2], aS[3] + mbF[3], spk, true);
    zpk = __builtin_amdgcn_cvt_pk_fp8_f32(aZ[0], aZ[1], zpk, false);
    zpk = __builtin_amdgcn_cvt_pk_fp8_f32(aZ[2], aZ[3], zpk, true);
    *(unsigned*)((char*)eS[b] + ezb) = spk;
    *(unsigned*)((char*)eZ[b] + ezb) = zpk;
    *(bf16x4*)((char*)eT[b] + ewb) = pT;

    soft_barrier();   // single lgkm-only barrier per tile

    {
      const long e = t * 16 + erow;
      const unsigned vS = *(const unsigned*)((const char*)eS[b] + zrb);
      const unsigned vZ = *(const unsigned*)((const char*)eZ[b] + zrb);
      const bf16x4 vT = *(const bf16x4*)((const char*)eT[b] + erb);
      *(unsigned*)(Sf8 + e * ND + c8 * 4) = vS;
      *(unsigned*)(Zf8 + e * ND + c8 * 4) = vZ;
      *(bf16x4*)(Tp + t * 2048 + erow * 128 + c8 * 4) = vT;   // tight pack
    }
    b ^= 1;
  }
}

// ---------------------------------------------------------------------------
// k23: fused gather + both GEMMs (r13-exact structure: tt kept, dual zbuf,
// no launch-bounds cap — r14's forced cap spilled to scratch, 3x regress).
// Only change vs r13: gather math vectorized (unpack_s/acc8 -> packed
// v_pk_add_f32), cutting the VALU chain between gather-return and barrier.
// ---------------------------------------------------------------------------
__global__ __launch_bounds__(512) void k23_fused(
    const u8* __restrict__ Zf8, const u8* __restrict__ Sf8,
    const int* __restrict__ adj, const u16* __restrict__ Tp,
    const u16* __restrict__ Wp_b, const u16* __restrict__ W2_b,
    const float* __restrict__ ub2, float* __restrict__ out)
{
  __shared__ u16 ht[32 * ND];   // 8 KB  hbar (bf16, swizzled)
  __shared__ u16 tt[32 * ND];   // 8 KB  T1
  __shared__ u16 ut[32 * ND];   // 8 KB  u exchange
  const int tid = threadIdx.x, wid = tid >> 6, lane = tid & 63;
  const int r = lane & 15, q = lane >> 4;
  const int ew = wid * 4 + q;          // edge-in-supertile
  const int c0 = r * 8;                // gather channel base (8 fp8 bytes)

  bf16x8 wpF[4], w2F[4];
  f32x4 ubF;
  {
    const int row = wid * 16 + r;
#pragma unroll
    for (int kk = 0; kk < 4; ++kk) {
      wpF[kk] = *(const bf16x8*)(Wp_b + row * ND + kk * 32 + q * 8);
      w2F[kk] = *(const bf16x8*)(W2_b + row * ND + kk * 32 + q * 8);
    }
    ubF = *(const f32x4*)(ub2 + wid * 16 + q * 4);
  }

  const int hwb = ew * 256 + ((r ^ (ew & 15)) << 4);
  const int trow = tid >> 4, tch = tid & 15;
  const int twb = trow * 256 + ((tch ^ (trow & 15)) << 4);
  const int uwb0 = (((wid * 2 + (q >> 1)) ^ r) << 4) | ((q & 1) << 3);

  const long stride = gridDim.x;
  long s = blockIdx.x;
  if (s >= NSUP) return;

  auto adjload = [&](long ss) { return adj[(ss * 32 + ew) * NK + r]; };

  // ---- prologue: gather-accumulate supertile s ----
  int myidxN;
  f32x4 haccA = {0.f, 0.f, 0.f, 0.f}, haccB = {0.f, 0.f, 0.f, 0.f};
  bf16x8 trC;
  {
    const int myidxC = adjload(s);
    const unsigned* sp = (const unsigned*)(Sf8 + (s * 32 + ew) * ND + c0);
    const unsigned sw0 = sp[0], sw1 = sp[1];
    trC = *(const bf16x8*)(Tp + s * 4096 + trow * 128 + tch * 8);
    const long s1 = s + stride;
    myidxN = (s1 < NSUP) ? adjload(s1) : 0;

    f32x4 sA, sB;
    unpack_s(sw0, sw1, sA, sB);
#pragma unroll
    for (int k = 0; k < NK; ++k) {
      const int n = __shfl(myidxC, (lane & 48) + k);
      const u32x2 zw = *(const u32x2*)(Zf8 + (long)n * ND + c0);
      acc8(haccA, haccB, sA, sB, zw);
    }
  }

  for (; s < NSUP; s += stride) {
    const long sn = s + stride, sn2 = sn + stride;
    const bool hasN = (sn < NSUP);

    // ---- A-store: hbar -> ht, T1 -> tt ----
    {
      bf16x8 hv;
#pragma unroll
      for (int i = 0; i < 4; ++i) {
        hv[i]     = (bf16_t)(haccA[i] * 0.0625f);
        hv[i + 4] = (bf16_t)(haccB[i] * 0.0625f);
      }
      *(bf16x8*)((char*)ht + hwb) = hv;
      *(bf16x8*)((char*)tt + twb) = trC;
    }

    // ---- prefetch burst A for sn: 8 Z-gathers + S + Tp + adj(sn2) ----
    u32x2 zbufA[8], zbufB[8];
    unsigned swn0 = 0, swn1 = 0;
    bf16x8 trN = {};
    int myidxN2 = 0;
    if (hasN) {
#pragma unroll
      for (int k = 0; k < 8; ++k) {
        const int n = __shfl(myidxN, (lane & 48) + k);
        zbufA[k] = *(const u32x2*)(Zf8 + (long)n * ND + c0);
      }
      const unsigned* sp = (const unsigned*)(Sf8 + (sn * 32 + ew) * ND + c0);
      swn0 = sp[0]; swn1 = sp[1];
      trN = *(const bf16x8*)(Tp + sn * 4096 + trow * 128 + tch * 8);
      if (sn2 < NSUP) myidxN2 = adjload(sn2);
    }

    soft_barrier();   // ht/tt visible; prefetch loads ride across

    // ---- phase B1: u = relu(T1 + hbar@Wp^T) ----
#pragma unroll
    for (int t2 = 0; t2 < 2; ++t2) {
      const int rowb = (t2 * 16 + r) * 256;
      bf16x8 hf[4];
#pragma unroll
      for (int kk = 0; kk < 4; ++kk)
        hf[kk] = *(const bf16x8*)((const char*)ht + rowb + (((kk * 4 + q) ^ r) << 4));
      f32x4 acc;
      {
        const bf16x4 tv = *(const bf16x4*)((const char*)tt + rowb + uwb0);
#pragma unroll
        for (int i = 0; i < 4; ++i) acc[i] = (float)tv[i];
      }
#pragma unroll
      for (int kk = 0; kk < 4; ++kk)
        acc = __builtin_amdgcn_mfma_f32_16x16x32_bf16(wpF[kk], hf[kk], acc, 0, 0, 0);
      bf16x4 u;
#pragma unroll
      for (int i = 0; i < 4; ++i) u[i] = (bf16_t)fmaxf(acc[i], 0.f);
      *(bf16x4*)((char*)ut + rowb + uwb0) = u;
    }

    // ---- prefetch burst B for sn ----
    if (hasN) {
#pragma unroll
      for (int k = 0; k < 8; ++k) {
        const int n = __shfl(myidxN, (lane & 48) + 8 + k);
        zbufB[k] = *(const u32x2*)(Zf8 + (long)n * ND + c0);
      }
    }

    soft_barrier();   // ut visible

    // ---- phase B2: out = u@uW2^T + ub2 ----
#pragma unroll
    for (int t2 = 0; t2 < 2; ++t2) {
      const int rowb = (t2 * 16 + r) * 256;
      bf16x8 uf[4];
#pragma unroll
      for (int kk = 0; kk < 4; ++kk)
        uf[kk] = *(const bf16x8*)((const char*)ut + rowb + (((kk * 4 + q) ^ r) << 4));
      f32x4 o = {0.f, 0.f, 0.f, 0.f};
#pragma unroll
      for (int kk = 0; kk < 4; ++kk)
        o = __builtin_amdgcn_mfma_f32_16x16x32_bf16(w2F[kk], uf[kk], o, 0, 0, 0);
#pragma unroll
      for (int i = 0; i < 4; ++i) o[i] += ubF[i];
      *(f32x4*)(out + (s * 32 + t2 * 16 + r) * ND + wid * 16 + q * 4) = o;
    }

    // ---- consume prefetched gathers for sn ----
    if (hasN) {
      f32x4 sA, sB;
      unpack_s(swn0, swn1, sA, sB);
      haccA = f32x4{0.f, 0.f, 0.f, 0.f};
      haccB = f32x4{0.f, 0.f, 0.f, 0.f};
#pragma unroll
      for (int k = 0; k < 8; ++k) acc8(haccA, haccB, sA, sB, zbufA[k]);
#pragma unroll
      for (int k = 0; k < 8; ++k) acc8(haccA, haccB, sA, sB, zbufB[k]);
      myidxN = myidxN2;
      trC = trN;
    }
  }
}

extern "C" void kernel_launch(void* const* d_in, const int* in_sizes, int n_in,
                              void* d_out, int out_size, void* d_ws, size_t ws_size,
                              hipStream_t stream)
{
  (void)in_sizes; (void)n_in; (void)out_size; (void)ws_size;
  const float* X   = (const float*)d_in[0];
  const int*   adj = (const int*)d_in[1];
  const float* mW1 = (const float*)d_in[2];
  const float* mb1 = (const float*)d_in[3];
  const float* mW2 = (const float*)d_in[4];
  const float* mb2 = (const float*)d_in[5];
  const float* uW1 = (const float*)d_in[6];
  const float* ub1 = (const float*)d_in[7];
  const float* uW2 = (const float*)d_in[8];
  const float* ub2 = (const float*)d_in[9];
  float* out = (float*)d_out;

  u8* ws8  = (u8*)d_ws;
  u8* Sf8  = ws8;                                // E*ND fp8 (12.8 MB)
  u8* Zf8  = Sf8 + (size_t)NE * ND;              // E*ND fp8 (12.8 MB)
  u16* Tp  = (u16*)(Zf8 + (size_t)NE * ND);      // packed T1 bf16 (25.6 MB, 2048 u16/tile)
  u16* Wi_b = Tp + (size_t)NE * ND;              // 128*128 bf16 each:
  u16* Wj_b = Wi_b + 128 * 128;
  u16* Ui_b = Wj_b + 128 * 128;
  u16* Wp_b = Ui_b + 128 * 128;
  u16* W2_b = Wp_b + 128 * 128;
  float* bp = (float*)(W2_b + 128 * 128);        // 128 f32

  k_prep<<<128, 128, 0, stream>>>(mW1, uW1, uW2, mW2, ub1, mb2,
                                  Wi_b, Wj_b, Ui_b, Wp_b, W2_b, bp);

  k1_szt<<<1024, 512, 0, stream>>>(X, Wi_b, Wj_b, Ui_b, mb1, bp, Sf8, Zf8, Tp);

  k23_fused<<<1024, 512, 0, stream>>>(Zf8, Sf8, adj, Tp, Wp_b, W2_b, ub2, out);
}